// Round 3
// baseline (675.115 us; speedup 1.0000x reference)
//
#include <hip/hip_runtime.h>
#include <hip/hip_cooperative_groups.h>

namespace cg = cooperative_groups;

#define NT 256
#define NB 256

struct Params {
  const float *X, *E, *nbr;
  const float *embW, *embB, *boutW, *boutB;
  const float *qpW, *qpB, *kpW, *kpB, *qoW, *qoB, *koW, *koB;
  const float *bpW, *bpB, *bowW, *bowB;
  const float *qlnG, *qlnB, *klnG, *klnB;
  float *out;
  float *q, *k, *pq, *pk, *pkT, *pred2, *genBias, *genDiff;
  int *map;
  float *specialDiff, *specialBias;
};

__device__ __forceinline__ float mishf(float x) {
  float sp = (x > 20.f) ? x : log1pf(expf(x));
  return x * tanhf(sp);
}

// one block per n (256 blocks x 256 threads), fully fused, 8 grid syncs
__global__ void __launch_bounds__(256, 1) crakn(Params P) {
  cg::grid_group grid = cg::this_grid();
  const int b = blockIdx.x, t = threadIdx.x;
  const int lane = t & 63, wave = t >> 6;
  __shared__ float smA[768];
  __shared__ float smB[512];
  __shared__ int smI[1025];

  // ================= Phase A: node/pred0/pairs/RBF =================
  {
    const int n = b;
    smA[t] = P.X[n * 256 + t];                 // stage X row
    __syncthreads();
    {                                          // node partials: wave = f-chunk
      const float* W = P.embW + wave * 64 * 64;
      const float* xr = smA + wave * 64;
      float acc = 0.f;
      #pragma unroll 8
      for (int f = 0; f < 64; ++f) acc = fmaf(xr[f], W[f * 64 + lane], acc);
      smB[t] = acc;
    }
    float pp = smA[t] * P.boutW[t];            // pred0 partial
    #pragma unroll
    for (int s = 32; s; s >>= 1) pp += __shfl_xor(pp, s);
    if (lane == 0) smA[512 + wave] = pp;
    __syncthreads();
    if (t < 64) {
      float nd = smB[t] + smB[64 + t] + smB[128 + t] + smB[192 + t] + P.embB[t];
      P.q[n * 64 + t] = nd;
      P.k[n * 64 + t] = nd;
    }
    if (t == 0) P.pred2[n] = smA[512] + smA[513] + smA[514] + smA[515] + P.boutB[0];
    if (n == 64 && t < 128) P.genBias[t] = 0.f;   // all-zero generic RBF row
    if (t < 25) ((float4*)(smA + 256))[t] = ((const float4*)(P.E + n * 100))[t];
    if (t == 0) smI[1024] = 0;
    __syncthreads();
    {                                          // distances, thread = m
      const int m = t;
      const float4* em = (const float4*)(P.E + m * 100);
      const float4* en = (const float4*)(smA + 256);
      float sq = 0.f;
      #pragma unroll 5
      for (int jj = 0; jj < 25; ++jj) {
        float4 a = en[jj], c = em[jj];
        float dx = a.x - c.x, dy = a.y - c.y, dz = a.z - c.z, dw = a.w - c.w;
        sq += dx * dx + dy * dy + dz * dz + dw * dw;
      }
      float dd = (sq > 0.f) ? sqrtf(sq) : 0.f;
      // exp(-127*(d-c)^2), c in [0,1]: underflows fp32 to exactly 0 for d >= 1.905
      bool special = dd < 1.905f;
      P.map[n * 256 + m] = special ? 1 : -1;
      if (special) {
        int idx = atomicAdd(&smI[1024], 1);
        smI[idx] = m;
        smB[idx] = dd;
      }
    }
    __syncthreads();
    {                                          // RBF rows, slot = n*256+m
      int cnt = smI[1024];
      for (int i = 0; i < cnt; ++i) {
        if (t < 128) {
          float dd = smB[i] - (float)t * (1.f / 127.f);
          P.specialBias[(size_t)((n << 8) | smI[i]) * 128 + t] = expf(-127.f * dd * dd);
        }
      }
    }
  }

  int curp = 0;
  for (int l = 0; l < 4; ++l) {
    grid.sync();
    // ================= Phase B1: q/k projections (all blocks, n = b) =========
    {
      const int n = b;
      if (t < 64) smA[t] = P.q[n * 64 + t];
      else if (t < 128) smA[t] = P.k[n * 64 + (t - 64)];
      __syncthreads();
      const float* Wq = P.qpW + (size_t)l * 32768;
      const float* Wk = P.kpW + (size_t)l * 32768;
      float aq0 = P.qpB[l * 512 + t], aq1 = P.qpB[l * 512 + 256 + t];
      float ak0 = P.kpB[l * 512 + t], ak1 = P.kpB[l * 512 + 256 + t];
      #pragma unroll 4
      for (int d = 0; d < 64; ++d) {
        float qd = smA[d], kd = smA[64 + d];
        aq0 = fmaf(qd, Wq[d * 512 + t], aq0);
        aq1 = fmaf(qd, Wq[d * 512 + 256 + t], aq1);
        ak0 = fmaf(kd, Wk[d * 512 + t], ak0);
        ak1 = fmaf(kd, Wk[d * 512 + 256 + t], ak1);
      }
      P.pq[n * 512 + t] = aq0;           P.pq[n * 512 + 256 + t] = aq1;
      P.pk[n * 512 + t] = ak0;           P.pk[n * 512 + 256 + t] = ak1;
      P.pkT[t * 256 + n] = ak0;          P.pkT[(256 + t) * 256 + n] = ak1;  // [c][m]
      __syncthreads();
    }
    // ================= Phase B2: bias pipeline (blocks 0..64) ================
    if (b < 65) {
      if (t == 0) smI[1024] = 0;
      __syncthreads();
      if (b < 64) {                       // collect special pairs of rows 4b..4b+3
        for (int idx = t; idx < 1024; idx += 256) {
          int n = (b << 2) + (idx >> 8), m = idx & 255;
          if (P.map[n * 256 + m] >= 0) {
            int w = atomicAdd(&smI[1024], 1);
            smI[w] = (n << 8) | m;
          }
        }
      }
      __syncthreads();
      const int npairs = smI[1024];
      const int total = npairs + (b == 64 ? 1 : 0);   // block 64: generic row
      const float* Wp = P.bpW + (size_t)l * 65536;
      const float* Wo = P.bowW + (size_t)l * 65536;
      for (int i = 0; i < total; ++i) {
        const bool gen = (i == npairs);
        float* row  = gen ? P.genBias : P.specialBias + (size_t)smI[i] * 128;
        float* drow = gen ? P.genDiff : P.specialDiff + (size_t)smI[i] * 4;
        if (t < 128) smA[t] = row[t];
        __syncthreads();
        float a0 = P.bpB[l * 512 + t], a1 = P.bpB[l * 512 + 256 + t];
        #pragma unroll 8
        for (int x = 0; x < 128; ++x) {
          float bv = smA[x];
          a0 = fmaf(bv, Wp[x * 512 + t], a0);
          a1 = fmaf(bv, Wp[x * 512 + 256 + t], a1);
        }
        smB[t] = a0; smB[256 + t] = a1;   // bb[512]
        __syncthreads();
        {                                  // per-head norms (wave = head)
          float e1 = smB[wave * 128 + lane], e2 = smB[wave * 128 + 64 + lane];
          float s = e1 * e1 + e2 * e2;
          #pragma unroll
          for (int sh = 32; sh; sh >>= 1) s += __shfl_xor(s, sh);
          if (lane == 0) drow[wave] = sqrtf(s);
        }
        {                                  // row' = mish(bb @ Wo + Bo), split K
          const int c = t & 127, half = t >> 7;
          const float* Woh = Wo + half * 256 * 128;
          const float* bbp = smB + half * 256;
          float acc = 0.f;
          #pragma unroll 8
          for (int o = 0; o < 256; ++o) acc = fmaf(bbp[o], Woh[o * 128 + c], acc);
          smA[128 + t] = acc;
        }
        __syncthreads();
        if (t < 128) row[t] = mishf(smA[128 + t] + smA[256 + t] + P.bowB[l * 128 + t]);
        __syncthreads();
      }
    }
    grid.sync();
    // ================= Phase C: attention + pred + q/k update (n = b) ========
    {
      const int n = b;
      smA[t] = P.pq[n * 512 + t];        smA[256 + t] = P.pq[n * 512 + 256 + t];
      smB[t] = P.pk[n * 512 + t];        smB[256 + t] = P.pk[n * 512 + 256 + t];
      const int m = t;
      const int sidx = P.map[n * 256 + m];
      const float val = (m == n) ? P.pred2[curp * 256 + n] : P.nbr[m];
      __syncthreads();
      float dot0 = 0.f, dot1 = 0.f, dot2 = 0.f, dot3 = 0.f;
      {
        const float* pt = P.pkT + m;
        #pragma unroll 4
        for (int j = 0; j < 128; ++j) {          // 4 heads at once, coalesced
          dot0 = fmaf(smA[j],       pt[(j      ) * 256], dot0);
          dot1 = fmaf(smA[128 + j], pt[(128 + j) * 256], dot1);
          dot2 = fmaf(smA[256 + j], pt[(256 + j) * 256], dot2);
          dot3 = fmaf(smA[384 + j], pt[(384 + j) * 256], dot3);
        }
      }
      float dots[4] = {dot0, dot1, dot2, dot3};
      float vsum = 0.f;
      #pragma unroll
      for (int h = 0; h < 4; ++h) {
        float lg = dots[h] * 0.08838834764831845f
                 + (sidx >= 0 ? P.specialDiff[(size_t)(n * 256 + m) * 4 + h] : P.genDiff[h]);
        float wm = lg;
        #pragma unroll
        for (int s = 32; s; s >>= 1) wm = fmaxf(wm, __shfl_xor(wm, s));
        if (lane == 0) smA[512 + h * 12 + wave] = wm;
        __syncthreads();
        float mx = fmaxf(fmaxf(smA[512 + h*12 + 0], smA[512 + h*12 + 1]),
                         fmaxf(smA[512 + h*12 + 2], smA[512 + h*12 + 3]));
        float e = expf(lg - mx);
        float s1 = e, s2 = e * val;
        #pragma unroll
        for (int s = 32; s; s >>= 1) { s1 += __shfl_xor(s1, s); s2 += __shfl_xor(s2, s); }
        if (lane == 0) { smA[512 + h*12 + 4 + wave] = s1; smA[512 + h*12 + 8 + wave] = s2; }
        __syncthreads();
        float denom = smA[512+h*12+4] + smA[512+h*12+5] + smA[512+h*12+6] + smA[512+h*12+7];
        float wsum  = smA[512+h*12+8] + smA[512+h*12+9] + smA[512+h*12+10] + smA[512+h*12+11];
        vsum += 0.25f * (wsum / denom);
      }
      if (t == 0) {
        P.pred2[(curp ^ 1) * 256 + n] = vsum;
        if (l == 3) P.out[n] = vsum;
      }
      __syncthreads();
      {                                   // q/k residual+mish+LN; waves: (which,half)
        const int which = t >> 7, d = t & 63, half = (t >> 6) & 1;
        const float* prow = which ? smB : smA;
        const float* W = (which ? P.koW : P.qoW) + (size_t)l * 32768 + half * 256 * 64;
        float acc = 0.f;
        #pragma unroll 8
        for (int rr = 0; rr < 256; ++rr) {
          int r = half * 256 + rr;
          acc = fmaf(prow[((r & 3) << 7) | (r >> 2)], W[rr * 64 + d], acc);
        }
        smA[512 + t] = acc;
      }
      __syncthreads();
      if (t < 128) {
        const int which = t >> 6, d = lane;
        float acc = smA[512 + which * 128 + d] + smA[512 + which * 128 + 64 + d]
                  + (which ? P.koB[l * 64 + d] : P.qoB[l * 64 + d]);
        float* x = (which ? P.k : P.q) + n * 64;
        float xv = x[d] + mishf(acc);
        float mean = xv;
        #pragma unroll
        for (int s = 32; s; s >>= 1) mean += __shfl_xor(mean, s);
        mean *= (1.f / 64.f);
        float dv = xv - mean, var = dv * dv;
        #pragma unroll
        for (int s = 32; s; s >>= 1) var += __shfl_xor(var, s);
        var *= (1.f / 64.f);
        const float* G  = (which ? P.klnG : P.qlnG) + l * 64;
        const float* Bb = (which ? P.klnB : P.qlnB) + l * 64;
        x[d] = dv * rsqrtf(var + 1e-5f) * G[d] + Bb[d];
      }
    }
    curp ^= 1;
  }
}

// ---------------------------------------------------------------------------
extern "C" void kernel_launch(void* const* d_in, const int* in_sizes, int n_in,
                              void* d_out, int out_size, void* d_ws, size_t ws_size,
                              hipStream_t stream) {
  char* p = (char*)d_ws;
  auto carve = [&](size_t bytes) -> void* {
    void* r = (void*)p;
    p += (bytes + 255) & ~(size_t)255;
    return r;
  };

  Params P;
  P.X     = (const float*)d_in[0];
  P.E     = (const float*)d_in[1];
  P.nbr   = (const float*)d_in[2];
  P.embW  = (const float*)d_in[3];
  P.embB  = (const float*)d_in[4];
  P.boutW = (const float*)d_in[5];
  P.boutB = (const float*)d_in[6];
  P.qpW   = (const float*)d_in[7];
  P.qpB   = (const float*)d_in[8];
  P.kpW   = (const float*)d_in[9];
  P.kpB   = (const float*)d_in[10];
  P.qoW   = (const float*)d_in[11];
  P.qoB   = (const float*)d_in[12];
  P.koW   = (const float*)d_in[13];
  P.koB   = (const float*)d_in[14];
  P.bpW   = (const float*)d_in[15];
  P.bpB   = (const float*)d_in[16];
  P.bowW  = (const float*)d_in[17];
  P.bowB  = (const float*)d_in[18];
  P.qlnG  = (const float*)d_in[19];
  P.qlnB  = (const float*)d_in[20];
  P.klnG  = (const float*)d_in[21];
  P.klnB  = (const float*)d_in[22];
  P.out   = (float*)d_out;

  P.q           = (float*)carve(256 * 64 * 4);
  P.k           = (float*)carve(256 * 64 * 4);
  P.pq          = (float*)carve(256 * 512 * 4);
  P.pk          = (float*)carve(256 * 512 * 4);
  P.pkT         = (float*)carve(512 * 256 * 4);
  P.pred2       = (float*)carve(2 * 256 * 4);
  P.genBias     = (float*)carve(128 * 4);
  P.genDiff     = (float*)carve(4 * 4);
  P.map         = (int*)carve((size_t)256 * 256 * 4);
  P.specialDiff = (float*)carve((size_t)65536 * 4 * 4);
  P.specialBias = (float*)carve((size_t)65536 * 128 * 4);

  void* args[] = { &P };
  hipLaunchCooperativeKernel((const void*)crakn, dim3(NB), dim3(NT), args, 0, stream);
}

// Round 6
// 427.478 us; speedup vs baseline: 1.5793x; 1.5793x over previous
//
#include <hip/hip_runtime.h>
#include <hip/hip_cooperative_groups.h>

namespace cg = cooperative_groups;

struct Params {
  const float *X, *E, *nbr;
  const float *embW, *embB, *boutW, *boutB;
  const float *qpW, *qpB, *kpW, *kpB, *qoW, *qoB, *koW, *koB;
  const float *bpW, *bpB, *bowW, *bowB;
  const float *qlnG, *qlnB, *klnG, *klnB;
  float *out;
  float *q, *k, *pq, *pk, *pkT, *pred;
  float *zeroBias, *zeroDiff, *genBias, *genDiff;
  int *map;
  float *specialDiff, *specialBias;
};

__device__ __forceinline__ float mishf(float x) {
  float sp = (x > 20.f) ? x : log1pf(expf(x));
  return x * tanhf(sp);
}

// One bias row through one layer (1024 threads, syncthreads inside):
//   b = row@Wp + Bp ; drow_h = ||b_h|| ; row' = mish(b@Wo + Bo)
__device__ void bias_row_pipe(float* __restrict__ row, float* __restrict__ drow,
                              const float* __restrict__ Wp, const float* __restrict__ Bp,
                              const float* __restrict__ Wo, const float* __restrict__ Bo,
                              float* smF, float* smG, int t) {
  const int lane = t & 63, wave = t >> 6;
  if (t < 128) smF[t] = row[t];
  __syncthreads();
  {                                     // GEMM1: split-K (2 halves of 64)
    const int o = t & 511, kh = t >> 9;
    const float* Wc = Wp + (kh * 64) * 512 + o;
    const float* rc = smF + kh * 64;
    float a = (kh == 0) ? Bp[o] : 0.f;
    #pragma unroll 8
    for (int c = 0; c < 64; ++c) a = fmaf(rc[c], Wc[c * 512], a);
    smG[t] = a;
  }
  __syncthreads();
  if (t < 512) smG[t] += smG[512 + t];  // b[512] in smG[0..511]
  __syncthreads();
  if (wave < 4) {                       // per-head norm, wave = head
    float e1 = smG[wave * 128 + lane], e2 = smG[wave * 128 + 64 + lane];
    float s = e1 * e1 + e2 * e2;
    #pragma unroll
    for (int sh = 32; sh; sh >>= 1) s += __shfl_xor(s, sh);
    if (lane == 0) drow[wave] = sqrtf(s);
  }
  {                                     // GEMM2: out c, 8 K-chunks of 64
    const int c = t & 127, ch = t >> 7;
    const float* Woc = Wo + (ch * 64) * 128 + c;
    const float* bc = smG + ch * 64;
    float a = 0.f;
    #pragma unroll 8
    for (int o2 = 0; o2 < 64; ++o2) a = fmaf(bc[o2], Woc[o2 * 128], a);
    smF[t] = a;
  }
  __syncthreads();
  if (t < 128) {
    float a = Bo[t];
    #pragma unroll
    for (int j = 0; j < 8; ++j) a += smF[t + 128 * j];
    row[t] = mishf(a);
  }
  __syncthreads();
}

// 256 blocks x 1024 threads (16 waves/CU, 1 block/CU)
__global__ void __launch_bounds__(1024, 4) crakn(Params P) {
  cg::grid_group grid = cg::this_grid();
  const int b = blockIdx.x, t = threadIdx.x;
  const int lane = t & 63, wave = t >> 6;
  __shared__ float smF[1024];
  __shared__ float smG[1024];
  __shared__ float smH[160];
  __shared__ int smI[260];

  // ================= Phase A: node / pred0 / distances / RBF =================
  {
    const int n = b;
    if (t < 256) smF[t] = P.X[n * 256 + t];
    __syncthreads();
    {                                   // node emb partials: d = t&63, 16 f-chunks
      const int d = t & 63, ch = t >> 6;
      const float* W = P.embW + (ch * 16) * 64 + d;
      const float* xr = smF + ch * 16;
      float acc = 0.f;
      #pragma unroll
      for (int f = 0; f < 16; ++f) acc = fmaf(xr[f], W[f * 64], acc);
      smG[t] = acc;
    }
    float pp = (t < 256) ? smF[t] * P.boutW[t] : 0.f;
    #pragma unroll
    for (int s = 32; s; s >>= 1) pp += __shfl_xor(pp, s);
    if (t < 256 && lane == 0) smH[wave] = pp;
    __syncthreads();
    if (t < 64) {
      float nd = P.embB[t];
      #pragma unroll
      for (int j = 0; j < 16; ++j) nd += smG[t + 64 * j];
      P.q[n * 64 + t] = nd; P.k[n * 64 + t] = nd;
    }
    if (t == 0) P.pred[n] = smH[0] + smH[1] + smH[2] + smH[3] + P.boutB[0];
    __syncthreads();
    if (t < 25) ((float4*)smG)[t] = ((const float4*)(P.E + n * 100))[t];
    if (t == 0) smI[256] = 0;
    __syncthreads();
    if (t < 256) {                      // distances, thread = m
      const int m = t;
      const float4* em = (const float4*)(P.E + m * 100);
      const float4* en = (const float4*)smG;
      float sq = 0.f;
      #pragma unroll 5
      for (int jj = 0; jj < 25; ++jj) {
        float4 a = en[jj], c = em[jj];
        float dx = a.x - c.x, dy = a.y - c.y, dz = a.z - c.z, dw = a.w - c.w;
        sq += dx * dx + dy * dy + dz * dz + dw * dw;
      }
      float dd = (sq > 0.f) ? sqrtf(sq) : 0.f;
      // exp(-127*(d-c)^2), c in [0,1]: fp32-underflows to exactly 0 for d>=1.905.
      // d==0 rows are all identical -> shared zero-row (exact dedup).
      int mv;
      if (dd == 0.f) mv = -2;
      else if (dd < 1.905f) {
        int i = atomicAdd(&smI[256], 1);
        smI[i] = m; smG[512 + i] = dd;
        mv = n * 256 + m;
      } else mv = -1;
      P.map[n * 256 + m] = mv;
    }
    __syncthreads();
    {                                   // rare per-pair RBF rows (none in practice)
      int cnt = smI[256]; if (cnt > 256) cnt = 256;
      for (int i = 0; i < cnt; ++i) if (t < 128) {
        float dd = smG[512 + i] - (float)t * (1.f / 127.f);
        P.specialBias[(size_t)(n * 256 + smI[i]) * 128 + t] = expf(-127.f * dd * dd);
      }
    }
    if (b == 0 && t < 128) {
      float c = (float)t * (1.f / 127.f);
      P.zeroBias[t] = expf(-127.f * c * c);  // d == 0 row
      P.genBias[t] = 0.f;                    // underflowed-to-zero row
    }
  }

  for (int l = 0; l < 4; ++l) {
    grid.sync();
    // ====== Phase B: qk-update + projections (block n = b handles q AND k) ======
    {
      const int n = b;
      const int group = t >> 9, u = t & 511;    // group 0 = q, 1 = k
      float* x = (group ? P.k : P.q) + n * 64;
      if (l > 0) {
        // NOTE: this applies the residual/LN update belonging to layer l-1
        // (it consumes layer l-1's pq/pk), so all params use lm1.
        const int lm1 = l - 1;
        smF[t] = (group ? P.pk : P.pq)[n * 512 + u];
        __syncthreads();
        const float* W = (group ? P.koW : P.qoW) + (size_t)lm1 * 32768;
        {
          const int d = u & 63, ch = u >> 6;    // 8 chunks x 64 rows
          const float* prow = smF + group * 512;
          float acc = 0.f;
          #pragma unroll 8
          for (int rr = 0; rr < 64; ++rr) {
            int r = ch * 64 + rr;
            acc = fmaf(prow[((r & 3) << 7) | (r >> 2)], W[r * 64 + d], acc);
          }
          smG[t] = acc;
        }
        __syncthreads();
        if (u < 64) {                           // one wave per group
          const float* B = (group ? P.koB : P.qoB) + lm1 * 64;
          float acc = B[u];
          #pragma unroll
          for (int j = 0; j < 8; ++j) acc += smG[group * 512 + u + 64 * j];
          float xv = x[u] + mishf(acc);
          float mean = xv;
          #pragma unroll
          for (int s = 32; s; s >>= 1) mean += __shfl_xor(mean, s);
          mean *= (1.f / 64.f);
          float dv = xv - mean, var = dv * dv;
          #pragma unroll
          for (int s = 32; s; s >>= 1) var += __shfl_xor(var, s);
          var *= (1.f / 64.f);
          const float* G  = (group ? P.klnG : P.qlnG) + lm1 * 64;
          const float* Bb = (group ? P.klnB : P.qlnB) + lm1 * 64;
          float xn = dv * rsqrtf(var + 1e-5f) * G[u] + Bb[u];
          x[u] = xn; smH[group * 64 + u] = xn;
        }
        __syncthreads();
      } else {
        if (u < 64) smH[group * 64 + u] = x[u];
        __syncthreads();
      }
      {                                         // projection: 1 col/thread
        const float* Wp = (group ? P.kpW : P.qpW) + (size_t)l * 32768;
        const float* Bp = (group ? P.kpB : P.qpB) + l * 512;
        const float* xs = smH + group * 64;
        float a = Bp[u];
        #pragma unroll 8
        for (int d = 0; d < 64; ++d) a = fmaf(xs[d], Wp[d * 512 + u], a);
        if (group) { P.pk[n * 512 + u] = a; P.pkT[u * 256 + n] = a; }
        else       { P.pq[n * 512 + u] = a; }
      }
      __syncthreads();
    }
    // ====== Phase B bias rows ======
    {
      if (t == 0) smI[256] = 0;
      __syncthreads();
      if (t < 256) {                            // rare-pair scan of own row
        int mv = P.map[b * 256 + t];
        if (mv >= 0) { int i = atomicAdd(&smI[256], 1); smI[i] = mv; }
      }
      __syncthreads();
      int cnt = smI[256]; if (cnt > 256) cnt = 256;
      for (int i = 0; i < cnt; ++i)
        bias_row_pipe(P.specialBias + (size_t)smI[i] * 128, P.specialDiff + (size_t)smI[i] * 4,
                      P.bpW + (size_t)l * 65536, P.bpB + l * 512,
                      P.bowW + (size_t)l * 65536, P.bowB + l * 128, smF, smG, t);
      if (b == 254)
        bias_row_pipe(P.zeroBias, P.zeroDiff, P.bpW + (size_t)l * 65536, P.bpB + l * 512,
                      P.bowW + (size_t)l * 65536, P.bowB + l * 128, smF, smG, t);
      if (b == 255)
        bias_row_pipe(P.genBias, P.genDiff, P.bpW + (size_t)l * 65536, P.bpB + l * 512,
                      P.bowW + (size_t)l * 65536, P.bowB + l * 128, smF, smG, t);
    }
    grid.sync();
    // ====== Phase C: attention + pred update (block n = b, 4 heads) ======
    {
      const int n = b;
      const int h = t >> 8, m = t & 255;
      if (t < 512) smF[t] = P.pq[n * 512 + t];
      __syncthreads();
      const int sidx = P.map[n * 256 + m];
      const float bdiff = (sidx == -2) ? P.zeroDiff[h]
                        : (sidx == -1) ? P.genDiff[h]
                        : P.specialDiff[(size_t)sidx * 4 + h];
      const float val = (m == n) ? P.pred[n] : P.nbr[m];
      const float* pt = P.pkT + (size_t)(h * 128) * 256 + m;
      const float* qv = smF + h * 128;
      float dot = 0.f;
      #pragma unroll 8
      for (int j = 0; j < 128; ++j) dot = fmaf(qv[j], pt[j * 256], dot);
      float lg = dot * 0.08838834764831845f + bdiff;   // 1/sqrt(128)
      float wm = lg;
      #pragma unroll
      for (int s = 32; s; s >>= 1) wm = fmaxf(wm, __shfl_xor(wm, s));
      if (lane == 0) smG[wave] = wm;
      __syncthreads();
      float mx = fmaxf(fmaxf(smG[h * 4], smG[h * 4 + 1]),
                       fmaxf(smG[h * 4 + 2], smG[h * 4 + 3]));
      float e = expf(lg - mx);
      float s1 = e, s2 = e * val;
      #pragma unroll
      for (int s = 32; s; s >>= 1) { s1 += __shfl_xor(s1, s); s2 += __shfl_xor(s2, s); }
      if (lane == 0) { smG[16 + wave] = s1; smG[32 + wave] = s2; }
      __syncthreads();
      if (t == 0) {
        float p = 0.f;
        #pragma unroll
        for (int hh = 0; hh < 4; ++hh) {
          float den = smG[16 + hh * 4] + smG[17 + hh * 4] + smG[18 + hh * 4] + smG[19 + hh * 4];
          float ws  = smG[32 + hh * 4] + smG[33 + hh * 4] + smG[34 + hh * 4] + smG[35 + hh * 4];
          p += 0.25f * (ws / den);
        }
        P.pred[n] = p;                 // only ever read by this block
        if (l == 3) P.out[n] = p;
      }
      __syncthreads();
    }
  }
}

// ---------------------------------------------------------------------------
extern "C" void kernel_launch(void* const* d_in, const int* in_sizes, int n_in,
                              void* d_out, int out_size, void* d_ws, size_t ws_size,
                              hipStream_t stream) {
  char* p = (char*)d_ws;
  auto carve = [&](size_t bytes) -> void* {
    void* r = (void*)p;
    p += (bytes + 255) & ~(size_t)255;
    return r;
  };

  Params P;
  P.X     = (const float*)d_in[0];
  P.E     = (const float*)d_in[1];
  P.nbr   = (const float*)d_in[2];
  P.embW  = (const float*)d_in[3];
  P.embB  = (const float*)d_in[4];
  P.boutW = (const float*)d_in[5];
  P.boutB = (const float*)d_in[6];
  P.qpW   = (const float*)d_in[7];
  P.qpB   = (const float*)d_in[8];
  P.kpW   = (const float*)d_in[9];
  P.kpB   = (const float*)d_in[10];
  P.qoW   = (const float*)d_in[11];
  P.qoB   = (const float*)d_in[12];
  P.koW   = (const float*)d_in[13];
  P.koB   = (const float*)d_in[14];
  P.bpW   = (const float*)d_in[15];
  P.bpB   = (const float*)d_in[16];
  P.bowW  = (const float*)d_in[17];
  P.bowB  = (const float*)d_in[18];
  P.qlnG  = (const float*)d_in[19];
  P.qlnB  = (const float*)d_in[20];
  P.klnG  = (const float*)d_in[21];
  P.klnB  = (const float*)d_in[22];
  P.out   = (float*)d_out;

  P.q           = (float*)carve(256 * 64 * 4);
  P.k           = (float*)carve(256 * 64 * 4);
  P.pq          = (float*)carve(256 * 512 * 4);
  P.pk          = (float*)carve(256 * 512 * 4);
  P.pkT         = (float*)carve(512 * 256 * 4);
  P.pred        = (float*)carve(256 * 4);
  P.zeroBias    = (float*)carve(128 * 4);
  P.zeroDiff    = (float*)carve(4 * 4);
  P.genBias     = (float*)carve(128 * 4);
  P.genDiff     = (float*)carve(4 * 4);
  P.map         = (int*)carve((size_t)256 * 256 * 4);
  P.specialDiff = (float*)carve((size_t)65536 * 4 * 4);
  P.specialBias = (float*)carve((size_t)65536 * 128 * 4);

  void* args[] = { &P };
  hipLaunchCooperativeKernel((const void*)crakn, dim3(256), dim3(1024), args, 0, stream);
}